// Round 1
// baseline (1711.993 us; speedup 1.0000x reference)
//
#include <hip/hip_runtime.h>
#include <limits.h>
#include <math.h>

// ---------- helpers: order-preserving float<->int for atomicMax ----------
__device__ __forceinline__ int f2oi(float f) {
    int i = __float_as_int(f);
    return i >= 0 ? i : (i ^ 0x7FFFFFFF);
}
__device__ __forceinline__ float oi2f(int i) {
    return __int_as_float(i >= 0 ? i : (i ^ 0x7FFFFFFF));
}

// ---------- GEMM: Hout[N,M] = X[N,128] @ W[M,128]^T ----------
// W staged in LDS with XOR swizzle (bank-conflict-free b128 reads), X rows via L1 broadcast.
template<int M, int NJ>
__global__ __launch_bounds__(256) void gemm_xwt(const float* __restrict__ X,
                                                const float* __restrict__ W,
                                                float* __restrict__ Hout, int N) {
    __shared__ float Wl[M * 128];
    for (int i = threadIdx.x; i < M * 32; i += 256) {
        int j = i >> 5, kg = i & 31;
        float4 w = reinterpret_cast<const float4*>(W)[i];
        int ks = (kg * 4) ^ ((j & 7) << 2);
        *reinterpret_cast<float4*>(&Wl[j * 128 + ks]) = w;
    }
    __syncthreads();
    int r = threadIdx.x >> 4;        // 0..15  (row within block tile)
    int lane16 = threadIdx.x & 15;   // column group
    long long row = (long long)blockIdx.x * 16 + r;
    if (row >= N) return;
    const float4* xrow = reinterpret_cast<const float4*>(X + row * 128);
    float acc[NJ];
#pragma unroll
    for (int jj = 0; jj < NJ; jj++) acc[jj] = 0.f;
#pragma unroll
    for (int kg = 0; kg < 32; kg++) {
        float4 xv = xrow[kg];
#pragma unroll
        for (int jj = 0; jj < NJ; jj++) {
            int j = lane16 + jj * 16;
            if (j < M) {
                const float4 wv = *reinterpret_cast<const float4*>(
                    &Wl[j * 128 + ((kg * 4) ^ ((j & 7) << 2))]);
                acc[jj] = fmaf(xv.x, wv.x,
                          fmaf(xv.y, wv.y,
                          fmaf(xv.z, wv.z,
                          fmaf(xv.w, wv.w, acc[jj]))));
            }
        }
    }
#pragma unroll
    for (int jj = 0; jj < NJ; jj++) {
        int j = lane16 + jj * 16;
        if (j < M) Hout[row * M + j] = acc[jj];
    }
}

// ---------- per-node attention logits: al_s[n,h] = sum_c h[n,h,c]*a_src[h,c] ----------
__global__ void attn_logits(const float* __restrict__ h, const float* __restrict__ a_src,
                            const float* __restrict__ a_dst, float* __restrict__ als,
                            float* __restrict__ ald, int N, int H, int C) {
    int idx = blockIdx.x * blockDim.x + threadIdx.x;
    if (idx >= N * H) return;
    int n = idx / H, hh = idx - n * H;
    const float* hp = h + (long long)n * H * C + hh * C;
    const float* as = a_src + hh * C;
    const float* ad = a_dst + hh * C;
    float s = 0.f, d = 0.f;
    for (int c = 0; c < C; c++) {
        float v = hp[c];
        s += v * as[c];
        d += v * ad[c];
    }
    als[idx] = s;
    ald[idx] = d;
}

// ---------- init m (ordered-int -inf) and den (0) ----------
__global__ void init_mden(int* __restrict__ m, float* __restrict__ den, int count) {
    int idx = blockIdx.x * blockDim.x + threadIdx.x;
    if (idx >= count) return;
    m[idx] = INT_MIN;
    den[idx] = 0.f;
}

// ---------- edge pass A: segment max of leaky_relu(al_s[src]+al_d[dst]) ----------
template<int H>
__global__ void edge_max(const int* __restrict__ src, const int* __restrict__ dst,
                         int E_real, int E_tot, const float* __restrict__ als,
                         const float* __restrict__ ald, int* __restrict__ m_int) {
    int e = blockIdx.x * blockDim.x + threadIdx.x;
    if (e >= E_tot) return;
    int s, d;
    if (e < E_real) { s = src[e]; d = dst[e]; } else { s = d = e - E_real; }
#pragma unroll
    for (int hh = 0; hh < H; hh++) {
        float v = als[s * H + hh] + ald[d * H + hh];
        v = v > 0.f ? v : 0.2f * v;
        atomicMax(&m_int[d * H + hh], f2oi(v));
    }
}

// ---------- edge pass B (layers 0/1): H=4, C=32, HC=128 ----------
__global__ void edge_accum128(const int* __restrict__ src, const int* __restrict__ dst,
                              int E_real, int E_tot, const float* __restrict__ h,
                              const float* __restrict__ als, const float* __restrict__ ald,
                              const int* __restrict__ m_int, float* __restrict__ den,
                              float* __restrict__ acc) {
    long long idx = (long long)blockIdx.x * blockDim.x + threadIdx.x;
    long long total = (long long)E_tot << 7;
    if (idx >= total) return;
    int e = (int)(idx >> 7);
    int hc = (int)(idx & 127);
    int s, d;
    if (e < E_real) { s = src[e]; d = dst[e]; } else { s = d = e - E_real; }
    int hh = hc >> 5;
    float v = als[s * 4 + hh] + ald[d * 4 + hh];
    v = v > 0.f ? v : 0.2f * v;
    float w = __expf(v - oi2f(m_int[d * 4 + hh]));
    if ((hc & 31) == 0) atomicAdd(&den[d * 4 + hh], w);
    atomicAdd(&acc[(long long)d * 128 + hc], h[(long long)s * 128 + hc] * w);
}

// ---------- edge pass B (layer 2): H=1, C=40 ----------
__global__ void edge_accum40(const int* __restrict__ src, const int* __restrict__ dst,
                             int E_real, int E_tot, const float* __restrict__ h,
                             const float* __restrict__ als, const float* __restrict__ ald,
                             const int* __restrict__ m_int, float* __restrict__ den,
                             float* __restrict__ acc) {
    int idx = blockIdx.x * blockDim.x + threadIdx.x;  // up to 34M, fits int
    int total = E_tot * 40;
    if (idx >= total) return;
    int e = idx / 40;
    int c = idx - e * 40;
    int s, d;
    if (e < E_real) { s = src[e]; d = dst[e]; } else { s = d = e - E_real; }
    float v = als[s] + ald[d];
    v = v > 0.f ? v : 0.2f * v;
    float w = __expf(v - oi2f(m_int[d]));
    if (c == 0) atomicAdd(&den[d], w);
    atomicAdd(&acc[d * 40 + c], h[s * 40 + c] * w);
}

// ---------- finalize layers 0/1: acc = elu(acc/den + b) in place ----------
__global__ void finalize_elu(float* __restrict__ acc, const float* __restrict__ den,
                             const float* __restrict__ b, int N) {
    long long idx = (long long)blockIdx.x * blockDim.x + threadIdx.x;
    if (idx >= (long long)N * 128) return;
    int n = (int)(idx >> 7);
    int hc = (int)(idx & 127);
    int hh = hc >> 5;
    float v = acc[idx] / den[n * 4 + hh] + b[hc];
    acc[idx] = v > 0.f ? v : expm1f(v);
}

// ---------- finalize layer 2 + log_softmax, in place on d_out ----------
__global__ __launch_bounds__(64) void finalize_lsm(float* __restrict__ out,
                                                   const float* __restrict__ den,
                                                   const float* __restrict__ b2, int N) {
    int n = blockIdx.x;
    int c = threadIdx.x;
    float val = -INFINITY;
    if (c < 40) val = out[n * 40 + c] / den[n] + b2[c];
    float mx = val;
#pragma unroll
    for (int o = 32; o >= 1; o >>= 1) mx = fmaxf(mx, __shfl_xor(mx, o, 64));
    float p = (c < 40) ? __expf(val - mx) : 0.f;
    float sum = p;
#pragma unroll
    for (int o = 32; o >= 1; o >>= 1) sum += __shfl_xor(sum, o, 64);
    if (c < 40) out[n * 40 + c] = val - mx - logf(sum);
}

extern "C" void kernel_launch(void* const* d_in, const int* in_sizes, int n_in,
                              void* d_out, int out_size, void* d_ws, size_t ws_size,
                              hipStream_t stream) {
    const float* x      = (const float*)d_in[0];
    const int*   ei     = (const int*)d_in[1];
    const float* W0     = (const float*)d_in[2];
    const float* a_src0 = (const float*)d_in[3];
    const float* a_dst0 = (const float*)d_in[4];
    const float* b0     = (const float*)d_in[5];
    const float* W1     = (const float*)d_in[6];
    const float* a_src1 = (const float*)d_in[7];
    const float* a_dst1 = (const float*)d_in[8];
    const float* b1     = (const float*)d_in[9];
    const float* W2     = (const float*)d_in[10];
    const float* a_src2 = (const float*)d_in[11];
    const float* a_dst2 = (const float*)d_in[12];
    const float* b2     = (const float*)d_in[13];

    const int N = in_sizes[0] / 128;          // 50000
    const int E_real = in_sizes[1] / 2;       // 800000
    const int E_tot = E_real + N;             // +self loops
    const int* src = ei;
    const int* dst = ei + E_real;

    unsigned char* ws = (unsigned char*)d_ws;
    const size_t szH = (size_t)N * 128 * sizeof(float);   // 25.6 MB
    float* bufH   = (float*)(ws);
    float* bufAcc = (float*)(ws + szH);
    float* als    = (float*)(ws + 2 * szH);
    float* ald    = (float*)(ws + 2 * szH + (size_t)N * 4 * sizeof(float));
    int*   m_int  = (int*)  (ws + 2 * szH + (size_t)N * 8 * sizeof(float));
    float* den    = (float*)(ws + 2 * szH + (size_t)N * 12 * sizeof(float));

    const int B = 256;
    const int gRows   = (N + 15) / 16;
    const int gNH4    = (N * 4 + B - 1) / B;
    const int gNH1    = (N + B - 1) / B;
    const int gEdge   = (E_tot + B - 1) / B;
    const int gAcc128 = (int)(((long long)E_tot * 128 + B - 1) / B);
    const int gAcc40  = (E_tot * 40 + B - 1) / B;
    const int gFin    = (int)(((long long)N * 128 + B - 1) / B);

    // ===== Layer 0 =====
    gemm_xwt<128, 8><<<gRows, B, 0, stream>>>(x, W0, bufH, N);
    attn_logits<<<gNH4, B, 0, stream>>>(bufH, a_src0, a_dst0, als, ald, N, 4, 32);
    init_mden<<<gNH4, B, 0, stream>>>(m_int, den, N * 4);
    hipMemsetAsync(bufAcc, 0, szH, stream);
    edge_max<4><<<gEdge, B, 0, stream>>>(src, dst, E_real, E_tot, als, ald, m_int);
    edge_accum128<<<gAcc128, B, 0, stream>>>(src, dst, E_real, E_tot, bufH, als, ald,
                                             m_int, den, bufAcc);
    finalize_elu<<<gFin, B, 0, stream>>>(bufAcc, den, b0, N);

    // ===== Layer 1 =====
    gemm_xwt<128, 8><<<gRows, B, 0, stream>>>(bufAcc, W1, bufH, N);
    attn_logits<<<gNH4, B, 0, stream>>>(bufH, a_src1, a_dst1, als, ald, N, 4, 32);
    init_mden<<<gNH4, B, 0, stream>>>(m_int, den, N * 4);
    hipMemsetAsync(bufAcc, 0, szH, stream);
    edge_max<4><<<gEdge, B, 0, stream>>>(src, dst, E_real, E_tot, als, ald, m_int);
    edge_accum128<<<gAcc128, B, 0, stream>>>(src, dst, E_real, E_tot, bufH, als, ald,
                                             m_int, den, bufAcc);
    finalize_elu<<<gFin, B, 0, stream>>>(bufAcc, den, b1, N);

    // ===== Layer 2 =====
    gemm_xwt<40, 3><<<gRows, B, 0, stream>>>(bufAcc, W2, bufH, N);
    attn_logits<<<gNH1, B, 0, stream>>>(bufH, a_src2, a_dst2, als, ald, N, 1, 40);
    init_mden<<<gNH1, B, 0, stream>>>(m_int, den, N);
    hipMemsetAsync(d_out, 0, (size_t)N * 40 * sizeof(float), stream);
    edge_max<1><<<gEdge, B, 0, stream>>>(src, dst, E_real, E_tot, als, ald, m_int);
    edge_accum40<<<gAcc40, B, 0, stream>>>(src, dst, E_real, E_tot, bufH, als, ald,
                                           m_int, den, (float*)d_out);
    finalize_lsm<<<N, 64, 0, stream>>>((float*)d_out, den, b2, N);
}

// Round 2
// 644.867 us; speedup vs baseline: 2.6548x; 2.6548x over previous
//
#include <hip/hip_runtime.h>
#include <math.h>

// ---------- GEMM: Hout[N,M] = X[N,128] @ W[M,128]^T ----------
template<int M, int NJ>
__global__ __launch_bounds__(256) void gemm_xwt(const float* __restrict__ X,
                                                const float* __restrict__ W,
                                                float* __restrict__ Hout, int N) {
    __shared__ float Wl[M * 128];
    for (int i = threadIdx.x; i < M * 32; i += 256) {
        int j = i >> 5, kg = i & 31;
        float4 w = reinterpret_cast<const float4*>(W)[i];
        int ks = (kg * 4) ^ ((j & 7) << 2);
        *reinterpret_cast<float4*>(&Wl[j * 128 + ks]) = w;
    }
    __syncthreads();
    int r = threadIdx.x >> 4;
    int lane16 = threadIdx.x & 15;
    long long row = (long long)blockIdx.x * 16 + r;
    if (row >= N) return;
    const float4* xrow = reinterpret_cast<const float4*>(X + row * 128);
    float acc[NJ];
#pragma unroll
    for (int jj = 0; jj < NJ; jj++) acc[jj] = 0.f;
#pragma unroll
    for (int kg = 0; kg < 32; kg++) {
        float4 xv = xrow[kg];
#pragma unroll
        for (int jj = 0; jj < NJ; jj++) {
            int j = lane16 + jj * 16;
            if (j < M) {
                const float4 wv = *reinterpret_cast<const float4*>(
                    &Wl[j * 128 + ((kg * 4) ^ ((j & 7) << 2))]);
                acc[jj] = fmaf(xv.x, wv.x,
                          fmaf(xv.y, wv.y,
                          fmaf(xv.z, wv.z,
                          fmaf(xv.w, wv.w, acc[jj]))));
            }
        }
    }
#pragma unroll
    for (int jj = 0; jj < NJ; jj++) {
        int j = lane16 + jj * 16;
        if (j < M) Hout[row * M + j] = acc[jj];
    }
}

// ---------- per-node attention logits ----------
__global__ void attn_logits(const float* __restrict__ h, const float* __restrict__ a_src,
                            const float* __restrict__ a_dst, float* __restrict__ als,
                            float* __restrict__ ald, int N, int H, int C) {
    int idx = blockIdx.x * blockDim.x + threadIdx.x;
    if (idx >= N * H) return;
    int n = idx / H, hh = idx - n * H;
    const float* hp = h + (long long)n * H * C + hh * C;
    const float* as = a_src + hh * C;
    const float* ad = a_dst + hh * C;
    float s = 0.f, d = 0.f;
    for (int c = 0; c < C; c++) {
        float v = hp[c];
        s += v * as[c];
        d += v * ad[c];
    }
    als[idx] = s;
    ald[idx] = d;
}

// ---------- CSR build ----------
__global__ void hist_dst(const int* __restrict__ dst, int E_real, int E_tot,
                         int* __restrict__ counts) {
    int e = blockIdx.x * blockDim.x + threadIdx.x;
    if (e >= E_tot) return;
    int d = (e < E_real) ? dst[e] : e - E_real;
    atomicAdd(&counts[d], 1);
}

__global__ __launch_bounds__(1024) void scan_counts(const int* __restrict__ counts,
                                                    int* __restrict__ offsets, int N) {
    __shared__ int part[1024];
    int tid = threadIdx.x;
    int per = (N + 1023) >> 10;
    int base = tid * per;
    int sum = 0;
    for (int i = 0; i < per; i++) {
        int idx = base + i;
        if (idx < N) sum += counts[idx];
    }
    part[tid] = sum;
    __syncthreads();
    for (int off = 1; off < 1024; off <<= 1) {
        int t = (tid >= off) ? part[tid - off] : 0;
        __syncthreads();
        part[tid] += t;
        __syncthreads();
    }
    int run = part[tid] - sum;  // exclusive prefix of this chunk
    for (int i = 0; i < per; i++) {
        int idx = base + i;
        if (idx < N) { offsets[idx] = run; run += counts[idx]; }
    }
    if (tid == 1023) offsets[N] = part[1023];
}

__global__ void copy_int(const int* __restrict__ a, int* __restrict__ b, int n) {
    int i = blockIdx.x * blockDim.x + threadIdx.x;
    if (i < n) b[i] = a[i];
}

__global__ void scatter_src(const int* __restrict__ src, const int* __restrict__ dst,
                            int E_real, int E_tot, int* __restrict__ cursor,
                            int* __restrict__ csr_src) {
    int e = blockIdx.x * blockDim.x + threadIdx.x;
    if (e >= E_tot) return;
    int s, d;
    if (e < E_real) { s = src[e]; d = dst[e]; } else { s = d = e - E_real; }
    int pos = atomicAdd(&cursor[d], 1);
    csr_src[pos] = s;
}

// ---------- fused GAT aggregate, layers 0/1 (H=4,C=32): one wave per node ----------
__global__ __launch_bounds__(64) void gat_agg128(const int* __restrict__ offsets,
                                                 const int* __restrict__ csr_src,
                                                 const float* __restrict__ h,
                                                 const float* __restrict__ als,
                                                 const float* __restrict__ ald,
                                                 const float* __restrict__ bias,
                                                 float* __restrict__ out, int N) {
    int n = blockIdx.x;
    int lane = threadIdx.x;
    int beg = offsets[n], end = offsets[n + 1];
    int h0 = lane >> 5;        // head of channel c0 = lane      (0 or 1)
    int h1 = 2 + h0;           // head of channel c1 = lane + 64 (2 or 3)
    float ad0 = ald[n * 4 + h0], ad1 = ald[n * 4 + h1];

    // pass 1: per-head max; lanes within each 32-half cover all edges (stride 32)
    float m0 = -INFINITY, m1 = -INFINITY;
    for (int p = beg + (lane & 31); p < end; p += 32) {
        int s = csr_src[p];
        float v0 = als[s * 4 + h0] + ad0; v0 = v0 > 0.f ? v0 : 0.2f * v0;
        float v1 = als[s * 4 + h1] + ad1; v1 = v1 > 0.f ? v1 : 0.2f * v1;
        m0 = fmaxf(m0, v0); m1 = fmaxf(m1, v1);
    }
#pragma unroll
    for (int off = 16; off >= 1; off >>= 1) {
        m0 = fmaxf(m0, __shfl_xor(m0, off, 64));
        m1 = fmaxf(m1, __shfl_xor(m1, off, 64));
    }

    // pass 2: all lanes walk every edge; weights redundant per lane, acc in regs
    float acc0 = 0.f, acc1 = 0.f, den0 = 0.f, den1 = 0.f;
    for (int p = beg; p < end; ++p) {
        int s = csr_src[p];
        float v0 = als[s * 4 + h0] + ad0; v0 = v0 > 0.f ? v0 : 0.2f * v0;
        float v1 = als[s * 4 + h1] + ad1; v1 = v1 > 0.f ? v1 : 0.2f * v1;
        float w0 = __expf(v0 - m0), w1 = __expf(v1 - m1);
        den0 += w0; den1 += w1;
        const float* hp = h + (long long)s * 128;
        acc0 = fmaf(hp[lane], w0, acc0);
        acc1 = fmaf(hp[lane + 64], w1, acc1);
    }
    float r0 = acc0 / den0 + bias[lane];
    float r1 = acc1 / den1 + bias[lane + 64];
    out[(long long)n * 128 + lane]      = r0 > 0.f ? r0 : expm1f(r0);
    out[(long long)n * 128 + lane + 64] = r1 > 0.f ? r1 : expm1f(r1);
}

// ---------- fused GAT aggregate + log_softmax, layer 2 (H=1,C=40) ----------
__global__ __launch_bounds__(64) void gat_agg40_lsm(const int* __restrict__ offsets,
                                                    const int* __restrict__ csr_src,
                                                    const float* __restrict__ h,
                                                    const float* __restrict__ als,
                                                    const float* __restrict__ ald,
                                                    const float* __restrict__ b2,
                                                    float* __restrict__ out, int N) {
    int n = blockIdx.x;
    int lane = threadIdx.x;
    int beg = offsets[n], end = offsets[n + 1];
    float ad = ald[n];

    float m = -INFINITY;
    for (int p = beg + lane; p < end; p += 64) {
        int s = csr_src[p];
        float v = als[s] + ad; v = v > 0.f ? v : 0.2f * v;
        m = fmaxf(m, v);
    }
#pragma unroll
    for (int off = 32; off >= 1; off >>= 1) m = fmaxf(m, __shfl_xor(m, off, 64));

    float acc = 0.f, den = 0.f;
    for (int p = beg; p < end; ++p) {
        int s = csr_src[p];
        float v = als[s] + ad; v = v > 0.f ? v : 0.2f * v;
        float w = __expf(v - m);
        den += w;
        if (lane < 40) acc = fmaf(h[(long long)s * 40 + lane], w, acc);
    }
    float val = (lane < 40) ? acc / den + b2[lane] : -INFINITY;
    float mx = val;
#pragma unroll
    for (int off = 32; off >= 1; off >>= 1) mx = fmaxf(mx, __shfl_xor(mx, off, 64));
    float p_ = (lane < 40) ? __expf(val - mx) : 0.f;
    float sum = p_;
#pragma unroll
    for (int off = 32; off >= 1; off >>= 1) sum += __shfl_xor(sum, off, 64);
    if (lane < 40) out[n * 40 + lane] = val - mx - logf(sum);
}

extern "C" void kernel_launch(void* const* d_in, const int* in_sizes, int n_in,
                              void* d_out, int out_size, void* d_ws, size_t ws_size,
                              hipStream_t stream) {
    const float* x      = (const float*)d_in[0];
    const int*   ei     = (const int*)d_in[1];
    const float* W0     = (const float*)d_in[2];
    const float* a_src0 = (const float*)d_in[3];
    const float* a_dst0 = (const float*)d_in[4];
    const float* b0     = (const float*)d_in[5];
    const float* W1     = (const float*)d_in[6];
    const float* a_src1 = (const float*)d_in[7];
    const float* a_dst1 = (const float*)d_in[8];
    const float* b1     = (const float*)d_in[9];
    const float* W2     = (const float*)d_in[10];
    const float* a_src2 = (const float*)d_in[11];
    const float* a_dst2 = (const float*)d_in[12];
    const float* b2     = (const float*)d_in[13];

    const int N = in_sizes[0] / 128;          // 50000
    const int E_real = in_sizes[1] / 2;       // 800000
    const int E_tot = E_real + N;
    const int* src = ei;
    const int* dst = ei + E_real;

    unsigned char* ws = (unsigned char*)d_ws;
    const size_t szH = (size_t)N * 128 * sizeof(float);
    float* bufH    = (float*)(ws);
    float* bufAcc  = (float*)(ws + szH);
    float* als     = (float*)(ws + 2 * szH);
    float* ald     = (float*)(ws + 2 * szH + (size_t)N * 4 * sizeof(float));
    int*   offsets = (int*)  (ws + 2 * szH + (size_t)N * 8 * sizeof(float));
    int*   counts  = offsets + (N + 1);
    int*   cursor  = counts + N;
    int*   csr_src = cursor + N;              // E_tot ints

    const int B = 256;
    const int gRows = (N + 15) / 16;
    const int gNH4  = (N * 4 + B - 1) / B;
    const int gNH1  = (N + B - 1) / B;
    const int gEdge = (E_tot + B - 1) / B;
    const int gN    = (N + B - 1) / B;

    // ===== CSR build (once; graph shared by all layers) =====
    hipMemsetAsync(counts, 0, (size_t)N * sizeof(int), stream);
    hist_dst<<<gEdge, B, 0, stream>>>(dst, E_real, E_tot, counts);
    scan_counts<<<1, 1024, 0, stream>>>(counts, offsets, N);
    copy_int<<<gN, B, 0, stream>>>(offsets, cursor, N);
    scatter_src<<<gEdge, B, 0, stream>>>(src, dst, E_real, E_tot, cursor, csr_src);

    // ===== Layer 0 =====
    gemm_xwt<128, 8><<<gRows, B, 0, stream>>>(x, W0, bufH, N);
    attn_logits<<<gNH4, B, 0, stream>>>(bufH, a_src0, a_dst0, als, ald, N, 4, 32);
    gat_agg128<<<N, 64, 0, stream>>>(offsets, csr_src, bufH, als, ald, b0, bufAcc, N);

    // ===== Layer 1 =====
    gemm_xwt<128, 8><<<gRows, B, 0, stream>>>(bufAcc, W1, bufH, N);
    attn_logits<<<gNH4, B, 0, stream>>>(bufH, a_src1, a_dst1, als, ald, N, 4, 32);
    gat_agg128<<<N, 64, 0, stream>>>(offsets, csr_src, bufH, als, ald, b1, bufAcc, N);

    // ===== Layer 2 =====
    gemm_xwt<40, 3><<<gRows, B, 0, stream>>>(bufAcc, W2, bufH, N);
    attn_logits<<<gNH1, B, 0, stream>>>(bufH, a_src2, a_dst2, als, ald, N, 1, 40);
    gat_agg40_lsm<<<N, 64, 0, stream>>>(offsets, csr_src, bufH, als, ald, b2,
                                        (float*)d_out, N);
}

// Round 3
// 550.840 us; speedup vs baseline: 3.1080x; 1.1707x over previous
//
#include <hip/hip_runtime.h>
#include <math.h>

// ---------- GEMM: Hout[N,M] = X[N,128] @ W[M,128]^T ----------
template<int M, int NJ>
__global__ __launch_bounds__(256) void gemm_xwt(const float* __restrict__ X,
                                                const float* __restrict__ W,
                                                float* __restrict__ Hout, int N) {
    __shared__ float Wl[M * 128];
    for (int i = threadIdx.x; i < M * 32; i += 256) {
        int j = i >> 5, kg = i & 31;
        float4 w = reinterpret_cast<const float4*>(W)[i];
        int ks = (kg * 4) ^ ((j & 7) << 2);
        *reinterpret_cast<float4*>(&Wl[j * 128 + ks]) = w;
    }
    __syncthreads();
    int r = threadIdx.x >> 4;
    int lane16 = threadIdx.x & 15;
    long long row = (long long)blockIdx.x * 16 + r;
    if (row >= N) return;
    const float4* xrow = reinterpret_cast<const float4*>(X + row * 128);
    float acc[NJ];
#pragma unroll
    for (int jj = 0; jj < NJ; jj++) acc[jj] = 0.f;
#pragma unroll
    for (int kg = 0; kg < 32; kg++) {
        float4 xv = xrow[kg];
#pragma unroll
        for (int jj = 0; jj < NJ; jj++) {
            int j = lane16 + jj * 16;
            if (j < M) {
                const float4 wv = *reinterpret_cast<const float4*>(
                    &Wl[j * 128 + ((kg * 4) ^ ((j & 7) << 2))]);
                acc[jj] = fmaf(xv.x, wv.x,
                          fmaf(xv.y, wv.y,
                          fmaf(xv.z, wv.z,
                          fmaf(xv.w, wv.w, acc[jj]))));
            }
        }
    }
#pragma unroll
    for (int jj = 0; jj < NJ; jj++) {
        int j = lane16 + jj * 16;
        if (j < M) Hout[row * M + j] = acc[jj];
    }
}

// ---------- per-node attention logits ----------
__global__ void attn_logits(const float* __restrict__ h, const float* __restrict__ a_src,
                            const float* __restrict__ a_dst, float* __restrict__ als,
                            float* __restrict__ ald, int N, int H, int C) {
    int idx = blockIdx.x * blockDim.x + threadIdx.x;
    if (idx >= N * H) return;
    int n = idx / H, hh = idx - n * H;
    const float* hp = h + (long long)n * H * C + hh * C;
    const float* as = a_src + hh * C;
    const float* ad = a_dst + hh * C;
    float s = 0.f, d = 0.f;
    for (int c = 0; c < C; c++) {
        float v = hp[c];
        s += v * as[c];
        d += v * ad[c];
    }
    als[idx] = s;
    ald[idx] = d;
}

// ---------- CSR build ----------
__global__ void hist_dst(const int* __restrict__ dst, int E_real, int E_tot,
                         int* __restrict__ counts) {
    int e = blockIdx.x * blockDim.x + threadIdx.x;
    if (e >= E_tot) return;
    int d = (e < E_real) ? dst[e] : e - E_real;
    atomicAdd(&counts[d], 1);
}

// multi-block scan: A) block-local scan of 1024-elem chunks
__global__ __launch_bounds__(256) void scanA(const int* __restrict__ counts,
                                             int* __restrict__ offsets,
                                             int* __restrict__ blockTot, int N) {
    __shared__ int sh[256];
    int tid = threadIdx.x;
    int base = blockIdx.x * 1024 + tid * 4;
    int v0 = 0, v1 = 0, v2 = 0, v3 = 0;
    if (base + 0 < N) v0 = counts[base + 0];
    if (base + 1 < N) v1 = counts[base + 1];
    if (base + 2 < N) v2 = counts[base + 2];
    if (base + 3 < N) v3 = counts[base + 3];
    int s = v0 + v1 + v2 + v3;
    sh[tid] = s;
    __syncthreads();
    for (int off = 1; off < 256; off <<= 1) {
        int t = (tid >= off) ? sh[tid - off] : 0;
        __syncthreads();
        sh[tid] += t;
        __syncthreads();
    }
    int run = sh[tid] - s;
    if (base + 0 < N) { offsets[base + 0] = run; run += v0; }
    if (base + 1 < N) { offsets[base + 1] = run; run += v1; }
    if (base + 2 < N) { offsets[base + 2] = run; run += v2; }
    if (base + 3 < N) { offsets[base + 3] = run; }
    if (tid == 255) blockTot[blockIdx.x] = sh[255];
}

// B) scan the block totals (<=256 of them), write grand total to offsets[N]
__global__ __launch_bounds__(256) void scanB(const int* __restrict__ blockTot,
                                             int* __restrict__ blockPre,
                                             int* __restrict__ offsets, int SB, int N) {
    __shared__ int sh[256];
    int tid = threadIdx.x;
    int v = (tid < SB) ? blockTot[tid] : 0;
    sh[tid] = v;
    __syncthreads();
    for (int off = 1; off < 256; off <<= 1) {
        int t = (tid >= off) ? sh[tid - off] : 0;
        __syncthreads();
        sh[tid] += t;
        __syncthreads();
    }
    blockPre[tid] = sh[tid] - v;
    if (tid == 255) offsets[N] = sh[255];
}

// C) add block prefixes; also produce cursor copy for scatter
__global__ __launch_bounds__(256) void scanC(int* __restrict__ offsets,
                                             int* __restrict__ cursor,
                                             const int* __restrict__ blockPre, int N) {
    int pre = blockPre[blockIdx.x];
    int base = blockIdx.x * 1024 + threadIdx.x * 4;
#pragma unroll
    for (int j = 0; j < 4; j++) {
        int i = base + j;
        if (i < N) {
            int o = offsets[i] + pre;
            offsets[i] = o;
            cursor[i] = o;
        }
    }
}

__global__ void scatter_src(const int* __restrict__ src, const int* __restrict__ dst,
                            int E_real, int E_tot, int* __restrict__ cursor,
                            int* __restrict__ csr_src) {
    int e = blockIdx.x * blockDim.x + threadIdx.x;
    if (e >= E_tot) return;
    int s, d;
    if (e < E_real) { s = src[e]; d = dst[e]; } else { s = d = e - E_real; }
    int pos = atomicAdd(&cursor[d], 1);
    csr_src[pos] = s;
}

// ---------- fused GAT aggregate, layers 0/1 (H=4,C=32) ----------
// One wave per node (grid-stride). Lane owns channels {2*lane, 2*lane+1}; head = lane>>4.
__global__ __launch_bounds__(256) void gat_agg128(const int* __restrict__ offsets,
                                                  const int* __restrict__ csr_src,
                                                  const float* __restrict__ h,
                                                  const float* __restrict__ als,
                                                  const float* __restrict__ ald,
                                                  const float* __restrict__ bias,
                                                  float* __restrict__ out, int N) {
    int gid = blockIdx.x * blockDim.x + threadIdx.x;
    int wid = gid >> 6;
    int lane = gid & 63;
    int nWaves = (gridDim.x * blockDim.x) >> 6;
    int hh = lane >> 4;
    const float2* h2 = (const float2*)h;
    float2 b2v = ((const float2*)bias)[lane];

    for (int n = wid; n < N; n += nWaves) {
        int beg = offsets[n], end = offsets[n + 1];
        float ad = ald[n * 4 + hh];

        // pass 1: per-head max (16 lanes of each head cover edges stride-16)
        float m = -INFINITY;
        for (int p = beg + (lane & 15); p < end; p += 16) {
            int s = csr_src[p];
            float v = als[s * 4 + hh] + ad;
            v = v > 0.f ? v : 0.2f * v;
            m = fmaxf(m, v);
        }
#pragma unroll
        for (int off = 8; off >= 1; off >>= 1) m = fmaxf(m, __shfl_xor(m, off, 64));

        // pass 2: walk edges, 2-way unrolled for MLP
        float accx = 0.f, accy = 0.f, den = 0.f;
        int p = beg;
        for (; p + 2 <= end; p += 2) {
            int s0 = csr_src[p], s1 = csr_src[p + 1];
            float a0 = als[s0 * 4 + hh], a1 = als[s1 * 4 + hh];
            float2 hv0 = h2[(long long)s0 * 64 + lane];
            float2 hv1 = h2[(long long)s1 * 64 + lane];
            float v0 = a0 + ad; v0 = v0 > 0.f ? v0 : 0.2f * v0;
            float v1 = a1 + ad; v1 = v1 > 0.f ? v1 : 0.2f * v1;
            float w0 = __expf(v0 - m), w1 = __expf(v1 - m);
            den += w0 + w1;
            accx = fmaf(hv0.x, w0, fmaf(hv1.x, w1, accx));
            accy = fmaf(hv0.y, w0, fmaf(hv1.y, w1, accy));
        }
        if (p < end) {
            int s0 = csr_src[p];
            float v0 = als[s0 * 4 + hh] + ad; v0 = v0 > 0.f ? v0 : 0.2f * v0;
            float w0 = __expf(v0 - m);
            den += w0;
            float2 hv0 = h2[(long long)s0 * 64 + lane];
            accx = fmaf(hv0.x, w0, accx);
            accy = fmaf(hv0.y, w0, accy);
        }
        float inv = 1.f / den;
        float r0 = accx * inv + b2v.x;
        float r1 = accy * inv + b2v.y;
        float2 o;
        o.x = r0 > 0.f ? r0 : expm1f(r0);
        o.y = r1 > 0.f ? r1 : expm1f(r1);
        ((float2*)out)[(long long)n * 64 + lane] = o;
    }
}

// ---------- fused GAT aggregate + log_softmax, layer 2 (H=1,C=40) ----------
__global__ __launch_bounds__(256) void gat_agg40_lsm(const int* __restrict__ offsets,
                                                     const int* __restrict__ csr_src,
                                                     const float* __restrict__ h,
                                                     const float* __restrict__ als,
                                                     const float* __restrict__ ald,
                                                     const float* __restrict__ b2,
                                                     float* __restrict__ out, int N) {
    int gid = blockIdx.x * blockDim.x + threadIdx.x;
    int wid = gid >> 6;
    int lane = gid & 63;
    int nWaves = (gridDim.x * blockDim.x) >> 6;

    for (int n = wid; n < N; n += nWaves) {
        int beg = offsets[n], end = offsets[n + 1];
        float ad = ald[n];

        float m = -INFINITY;
        for (int p = beg + lane; p < end; p += 64) {
            int s = csr_src[p];
            float v = als[s] + ad; v = v > 0.f ? v : 0.2f * v;
            m = fmaxf(m, v);
        }
#pragma unroll
        for (int off = 32; off >= 1; off >>= 1) m = fmaxf(m, __shfl_xor(m, off, 64));

        float acc = 0.f, den = 0.f;
        int p = beg;
        for (; p + 2 <= end; p += 2) {
            int s0 = csr_src[p], s1 = csr_src[p + 1];
            float a0 = als[s0], a1 = als[s1];
            float hv0 = (lane < 40) ? h[(long long)s0 * 40 + lane] : 0.f;
            float hv1 = (lane < 40) ? h[(long long)s1 * 40 + lane] : 0.f;
            float v0 = a0 + ad; v0 = v0 > 0.f ? v0 : 0.2f * v0;
            float v1 = a1 + ad; v1 = v1 > 0.f ? v1 : 0.2f * v1;
            float w0 = __expf(v0 - m), w1 = __expf(v1 - m);
            den += w0 + w1;
            acc = fmaf(hv0, w0, fmaf(hv1, w1, acc));
        }
        if (p < end) {
            int s0 = csr_src[p];
            float v0 = als[s0] + ad; v0 = v0 > 0.f ? v0 : 0.2f * v0;
            float w0 = __expf(v0 - m);
            den += w0;
            if (lane < 40) acc = fmaf(h[(long long)s0 * 40 + lane], w0, acc);
        }
        float val = (lane < 40) ? acc / den + b2[lane] : -INFINITY;
        float mx = val;
#pragma unroll
        for (int off = 32; off >= 1; off >>= 1) mx = fmaxf(mx, __shfl_xor(mx, off, 64));
        float pe = (lane < 40) ? __expf(val - mx) : 0.f;
        float sum = pe;
#pragma unroll
        for (int off = 32; off >= 1; off >>= 1) sum += __shfl_xor(sum, off, 64);
        if (lane < 40) out[n * 40 + lane] = val - mx - logf(sum);
    }
}

extern "C" void kernel_launch(void* const* d_in, const int* in_sizes, int n_in,
                              void* d_out, int out_size, void* d_ws, size_t ws_size,
                              hipStream_t stream) {
    const float* x      = (const float*)d_in[0];
    const int*   ei     = (const int*)d_in[1];
    const float* W0     = (const float*)d_in[2];
    const float* a_src0 = (const float*)d_in[3];
    const float* a_dst0 = (const float*)d_in[4];
    const float* b0     = (const float*)d_in[5];
    const float* W1     = (const float*)d_in[6];
    const float* a_src1 = (const float*)d_in[7];
    const float* a_dst1 = (const float*)d_in[8];
    const float* b1     = (const float*)d_in[9];
    const float* W2     = (const float*)d_in[10];
    const float* a_src2 = (const float*)d_in[11];
    const float* a_dst2 = (const float*)d_in[12];
    const float* b2     = (const float*)d_in[13];

    const int N = in_sizes[0] / 128;          // 50000
    const int E_real = in_sizes[1] / 2;       // 800000
    const int E_tot = E_real + N;
    const int* src = ei;
    const int* dst = ei + E_real;

    unsigned char* ws = (unsigned char*)d_ws;
    const size_t szH = (size_t)N * 128 * sizeof(float);
    float* bufH     = (float*)(ws);
    float* bufAcc   = (float*)(ws + szH);
    float* als      = (float*)(ws + 2 * szH);
    float* ald      = (float*)(ws + 2 * szH + (size_t)N * 4 * sizeof(float));
    int*   offsets  = (int*)  (ws + 2 * szH + (size_t)N * 8 * sizeof(float));
    int*   counts   = offsets + (N + 1);
    int*   cursor   = counts + N;
    int*   blockTot = cursor + N;
    int*   blockPre = blockTot + 256;
    int*   csr_src  = blockPre + 256;         // E_tot ints

    const int B = 256;
    const int gRows = (N + 15) / 16;
    const int gNH4  = (N * 4 + B - 1) / B;
    const int gNH1  = (N + B - 1) / B;
    const int gEdge = (E_tot + B - 1) / B;
    const int SB    = (N + 1023) / 1024;      // 49 scan blocks
    const int gAgg  = 2048;                   // 8192 waves grid-stride

    // ===== CSR build (once) =====
    hipMemsetAsync(counts, 0, (size_t)N * sizeof(int), stream);
    hist_dst<<<gEdge, B, 0, stream>>>(dst, E_real, E_tot, counts);
    scanA<<<SB, B, 0, stream>>>(counts, offsets, blockTot, N);
    scanB<<<1, B, 0, stream>>>(blockTot, blockPre, offsets, SB, N);
    scanC<<<SB, B, 0, stream>>>(offsets, cursor, blockPre, N);
    scatter_src<<<gEdge, B, 0, stream>>>(src, dst, E_real, E_tot, cursor, csr_src);

    // ===== Layer 0 =====
    gemm_xwt<128, 8><<<gRows, B, 0, stream>>>(x, W0, bufH, N);
    attn_logits<<<gNH4, B, 0, stream>>>(bufH, a_src0, a_dst0, als, ald, N, 4, 32);
    gat_agg128<<<gAgg, B, 0, stream>>>(offsets, csr_src, bufH, als, ald, b0, bufAcc, N);

    // ===== Layer 1 =====
    gemm_xwt<128, 8><<<gRows, B, 0, stream>>>(bufAcc, W1, bufH, N);
    attn_logits<<<gNH4, B, 0, stream>>>(bufH, a_src1, a_dst1, als, ald, N, 4, 32);
    gat_agg128<<<gAgg, B, 0, stream>>>(offsets, csr_src, bufH, als, ald, b1, bufAcc, N);

    // ===== Layer 2 =====
    gemm_xwt<40, 3><<<gRows, B, 0, stream>>>(bufAcc, W2, bufH, N);
    attn_logits<<<gNH1, B, 0, stream>>>(bufH, a_src2, a_dst2, als, ald, N, 1, 40);
    gat_agg40_lsm<<<gAgg, B, 0, stream>>>(offsets, csr_src, bufH, als, ald, b2,
                                          (float*)d_out, N);
}

// Round 4
// 434.800 us; speedup vs baseline: 3.9374x; 1.2669x over previous
//
#include <hip/hip_runtime.h>
#include <math.h>

// ---------- GEMM + fused attention logits ----------
// Hout[N,M] = X[N,128] @ W[M,128]^T ; als/ald[n,h] = sum_c Hout[n,h*C+c]*a_{src,dst}[h,c]
// Block: 256 threads, 64 rows. Thread: 4 rows (rb, rb+16, rb+32, rb+48) x 8 cols (lane16+16*jj).
template<int M, int NJ, int H>
__global__ __launch_bounds__(256) void gemm_logits(const float* __restrict__ X,
                                                   const float* __restrict__ W,
                                                   const float* __restrict__ a_src,
                                                   const float* __restrict__ a_dst,
                                                   float* __restrict__ Hout,
                                                   float* __restrict__ als,
                                                   float* __restrict__ ald, int N) {
    __shared__ float Wl[M * 128];
    for (int i = threadIdx.x; i < M * 32; i += 256) {
        int j = i >> 5, kg = i & 31;
        float4 w = reinterpret_cast<const float4*>(W)[i];
        int ks = (kg * 4) ^ ((j & 7) << 2);
        *reinterpret_cast<float4*>(&Wl[j * 128 + ks]) = w;
    }
    __syncthreads();

    int lane16 = threadIdx.x & 15;
    int rb = threadIdx.x >> 4;              // 0..15
    int base = blockIdx.x * 64;

    // clamped row pointers (row>=N reads row 0, discarded at store)
    const float4* xr[4];
    int rows[4];
#pragma unroll
    for (int q = 0; q < 4; q++) {
        int row = base + rb + q * 16;
        rows[q] = row;
        int rc = row < N ? row : 0;
        xr[q] = reinterpret_cast<const float4*>(X + (long long)rc * 128);
    }

    float acc[4][NJ];
#pragma unroll
    for (int q = 0; q < 4; q++)
#pragma unroll
        for (int jj = 0; jj < NJ; jj++) acc[q][jj] = 0.f;

#pragma unroll 4
    for (int kg = 0; kg < 32; kg++) {
        float4 xv0 = xr[0][kg];
        float4 xv1 = xr[1][kg];
        float4 xv2 = xr[2][kg];
        float4 xv3 = xr[3][kg];
#pragma unroll
        for (int jj = 0; jj < NJ; jj++) {
            int j = lane16 + jj * 16;
            if (M == 128 || j < M) {
                const float4 wv = *reinterpret_cast<const float4*>(
                    &Wl[j * 128 + ((kg * 4) ^ ((j & 7) << 2))]);
                acc[0][jj] = fmaf(xv0.x, wv.x, fmaf(xv0.y, wv.y, fmaf(xv0.z, wv.z, fmaf(xv0.w, wv.w, acc[0][jj]))));
                acc[1][jj] = fmaf(xv1.x, wv.x, fmaf(xv1.y, wv.y, fmaf(xv1.z, wv.z, fmaf(xv1.w, wv.w, acc[1][jj]))));
                acc[2][jj] = fmaf(xv2.x, wv.x, fmaf(xv2.y, wv.y, fmaf(xv2.z, wv.z, fmaf(xv2.w, wv.w, acc[2][jj]))));
                acc[3][jj] = fmaf(xv3.x, wv.x, fmaf(xv3.y, wv.y, fmaf(xv3.z, wv.z, fmaf(xv3.w, wv.w, acc[3][jj]))));
            }
        }
    }

    // attention vectors: flat index of (head=j/C, c=j%C) equals j for both layouts here
    float asv[NJ], adv[NJ];
#pragma unroll
    for (int jj = 0; jj < NJ; jj++) {
        int j = lane16 + jj * 16;
        asv[jj] = (j < M) ? a_src[j] : 0.f;
        adv[jj] = (j < M) ? a_dst[j] : 0.f;
    }

#pragma unroll
    for (int q = 0; q < 4; q++) {
        int row = rows[q];
        float hs[H], hd[H];
#pragma unroll
        for (int h = 0; h < H; h++) { hs[h] = 0.f; hd[h] = 0.f; }
#pragma unroll
        for (int jj = 0; jj < NJ; jj++) {
            int h = (H == 1) ? 0 : (jj >> 1);
            hs[h] = fmaf(acc[q][jj], asv[jj], hs[h]);
            hd[h] = fmaf(acc[q][jj], adv[jj], hd[h]);
        }
#pragma unroll
        for (int off = 8; off >= 1; off >>= 1) {
#pragma unroll
            for (int h = 0; h < H; h++) {
                hs[h] += __shfl_xor(hs[h], off, 64);
                hd[h] += __shfl_xor(hd[h], off, 64);
            }
        }
        if (row < N) {
            if (lane16 < H) als[row * H + lane16] = hs[lane16];
            if (lane16 >= 8 && lane16 < 8 + H) ald[row * H + (lane16 - 8)] = hd[lane16 - 8];
#pragma unroll
            for (int jj = 0; jj < NJ; jj++) {
                int j = lane16 + jj * 16;
                if (j < M) Hout[(long long)row * M + j] = acc[q][jj];
            }
        }
    }
}

// ---------- CSR build ----------
__global__ void hist_dst(const int* __restrict__ dst, int E_real, int E_tot,
                         int* __restrict__ counts) {
    int e = blockIdx.x * blockDim.x + threadIdx.x;
    if (e >= E_tot) return;
    int d = (e < E_real) ? dst[e] : e - E_real;
    atomicAdd(&counts[d], 1);
}

__global__ __launch_bounds__(256) void scanA(const int* __restrict__ counts,
                                             int* __restrict__ offsets,
                                             int* __restrict__ blockTot, int N) {
    __shared__ int sh[256];
    int tid = threadIdx.x;
    int base = blockIdx.x * 1024 + tid * 4;
    int v0 = 0, v1 = 0, v2 = 0, v3 = 0;
    if (base + 0 < N) v0 = counts[base + 0];
    if (base + 1 < N) v1 = counts[base + 1];
    if (base + 2 < N) v2 = counts[base + 2];
    if (base + 3 < N) v3 = counts[base + 3];
    int s = v0 + v1 + v2 + v3;
    sh[tid] = s;
    __syncthreads();
    for (int off = 1; off < 256; off <<= 1) {
        int t = (tid >= off) ? sh[tid - off] : 0;
        __syncthreads();
        sh[tid] += t;
        __syncthreads();
    }
    int run = sh[tid] - s;
    if (base + 0 < N) { offsets[base + 0] = run; run += v0; }
    if (base + 1 < N) { offsets[base + 1] = run; run += v1; }
    if (base + 2 < N) { offsets[base + 2] = run; run += v2; }
    if (base + 3 < N) { offsets[base + 3] = run; }
    if (tid == 255) blockTot[blockIdx.x] = sh[255];
}

__global__ __launch_bounds__(256) void scanB(const int* __restrict__ blockTot,
                                             int* __restrict__ blockPre,
                                             int* __restrict__ offsets, int SB, int N) {
    __shared__ int sh[256];
    int tid = threadIdx.x;
    int v = (tid < SB) ? blockTot[tid] : 0;
    sh[tid] = v;
    __syncthreads();
    for (int off = 1; off < 256; off <<= 1) {
        int t = (tid >= off) ? sh[tid - off] : 0;
        __syncthreads();
        sh[tid] += t;
        __syncthreads();
    }
    blockPre[tid] = sh[tid] - v;
    if (tid == 255) offsets[N] = sh[255];
}

__global__ __launch_bounds__(256) void scanC(int* __restrict__ offsets,
                                             int* __restrict__ cursor,
                                             const int* __restrict__ blockPre, int N) {
    int pre = blockPre[blockIdx.x];
    int base = blockIdx.x * 1024 + threadIdx.x * 4;
#pragma unroll
    for (int j = 0; j < 4; j++) {
        int i = base + j;
        if (i < N) {
            int o = offsets[i] + pre;
            offsets[i] = o;
            cursor[i] = o;
        }
    }
}

__global__ void scatter_src(const int* __restrict__ src, const int* __restrict__ dst,
                            int E_real, int E_tot, int* __restrict__ cursor,
                            int* __restrict__ csr_src) {
    int e = blockIdx.x * blockDim.x + threadIdx.x;
    if (e >= E_tot) return;
    int s, d;
    if (e < E_real) { s = src[e]; d = dst[e]; } else { s = d = e - E_real; }
    int pos = atomicAdd(&cursor[d], 1);
    csr_src[pos] = s;
}

// ---------- fused GAT aggregate, layers 0/1 (H=4,C=32) ----------
__global__ __launch_bounds__(256) void gat_agg128(const int* __restrict__ offsets,
                                                  const int* __restrict__ csr_src,
                                                  const float* __restrict__ h,
                                                  const float* __restrict__ als,
                                                  const float* __restrict__ ald,
                                                  const float* __restrict__ bias,
                                                  float* __restrict__ out, int N) {
    int gid = blockIdx.x * blockDim.x + threadIdx.x;
    int wid = gid >> 6;
    int lane = gid & 63;
    int nWaves = (gridDim.x * blockDim.x) >> 6;
    int hh = lane >> 4;
    const float2* h2 = (const float2*)h;
    float2 b2v = ((const float2*)bias)[lane];

    for (int n = wid; n < N; n += nWaves) {
        int beg = offsets[n], end = offsets[n + 1];
        float ad = ald[n * 4 + hh];

        float m = -INFINITY;
        for (int p = beg + (lane & 15); p < end; p += 16) {
            int s = csr_src[p];
            float v = als[s * 4 + hh] + ad;
            v = v > 0.f ? v : 0.2f * v;
            m = fmaxf(m, v);
        }
#pragma unroll
        for (int off = 8; off >= 1; off >>= 1) m = fmaxf(m, __shfl_xor(m, off, 64));

        float accx = 0.f, accy = 0.f, den = 0.f;
        int p = beg;
        for (; p + 2 <= end; p += 2) {
            int s0 = csr_src[p], s1 = csr_src[p + 1];
            float a0 = als[s0 * 4 + hh], a1 = als[s1 * 4 + hh];
            float2 hv0 = h2[(long long)s0 * 64 + lane];
            float2 hv1 = h2[(long long)s1 * 64 + lane];
            float v0 = a0 + ad; v0 = v0 > 0.f ? v0 : 0.2f * v0;
            float v1 = a1 + ad; v1 = v1 > 0.f ? v1 : 0.2f * v1;
            float w0 = __expf(v0 - m), w1 = __expf(v1 - m);
            den += w0 + w1;
            accx = fmaf(hv0.x, w0, fmaf(hv1.x, w1, accx));
            accy = fmaf(hv0.y, w0, fmaf(hv1.y, w1, accy));
        }
        if (p < end) {
            int s0 = csr_src[p];
            float v0 = als[s0 * 4 + hh] + ad; v0 = v0 > 0.f ? v0 : 0.2f * v0;
            float w0 = __expf(v0 - m);
            den += w0;
            float2 hv0 = h2[(long long)s0 * 64 + lane];
            accx = fmaf(hv0.x, w0, accx);
            accy = fmaf(hv0.y, w0, accy);
        }
        float inv = 1.f / den;
        float r0 = accx * inv + b2v.x;
        float r1 = accy * inv + b2v.y;
        float2 o;
        o.x = r0 > 0.f ? r0 : expm1f(r0);
        o.y = r1 > 0.f ? r1 : expm1f(r1);
        ((float2*)out)[(long long)n * 64 + lane] = o;
    }
}

// ---------- fused GAT aggregate + log_softmax, layer 2 (H=1,C=40) ----------
__global__ __launch_bounds__(256) void gat_agg40_lsm(const int* __restrict__ offsets,
                                                     const int* __restrict__ csr_src,
                                                     const float* __restrict__ h,
                                                     const float* __restrict__ als,
                                                     const float* __restrict__ ald,
                                                     const float* __restrict__ b2,
                                                     float* __restrict__ out, int N) {
    int gid = blockIdx.x * blockDim.x + threadIdx.x;
    int wid = gid >> 6;
    int lane = gid & 63;
    int nWaves = (gridDim.x * blockDim.x) >> 6;

    for (int n = wid; n < N; n += nWaves) {
        int beg = offsets[n], end = offsets[n + 1];
        float ad = ald[n];

        float m = -INFINITY;
        for (int p = beg + lane; p < end; p += 64) {
            int s = csr_src[p];
            float v = als[s] + ad; v = v > 0.f ? v : 0.2f * v;
            m = fmaxf(m, v);
        }
#pragma unroll
        for (int off = 32; off >= 1; off >>= 1) m = fmaxf(m, __shfl_xor(m, off, 64));

        float acc = 0.f, den = 0.f;
        int p = beg;
        for (; p + 2 <= end; p += 2) {
            int s0 = csr_src[p], s1 = csr_src[p + 1];
            float a0 = als[s0], a1 = als[s1];
            float hv0 = (lane < 40) ? h[(long long)s0 * 40 + lane] : 0.f;
            float hv1 = (lane < 40) ? h[(long long)s1 * 40 + lane] : 0.f;
            float v0 = a0 + ad; v0 = v0 > 0.f ? v0 : 0.2f * v0;
            float v1 = a1 + ad; v1 = v1 > 0.f ? v1 : 0.2f * v1;
            float w0 = __expf(v0 - m), w1 = __expf(v1 - m);
            den += w0 + w1;
            acc = fmaf(hv0, w0, fmaf(hv1, w1, acc));
        }
        if (p < end) {
            int s0 = csr_src[p];
            float v0 = als[s0] + ad; v0 = v0 > 0.f ? v0 : 0.2f * v0;
            float w0 = __expf(v0 - m);
            den += w0;
            if (lane < 40) acc = fmaf(h[(long long)s0 * 40 + lane], w0, acc);
        }
        float val = (lane < 40) ? acc / den + b2[lane] : -INFINITY;
        float mx = val;
#pragma unroll
        for (int off = 32; off >= 1; off >>= 1) mx = fmaxf(mx, __shfl_xor(mx, off, 64));
        float pe = (lane < 40) ? __expf(val - mx) : 0.f;
        float sum = pe;
#pragma unroll
        for (int off = 32; off >= 1; off >>= 1) sum += __shfl_xor(sum, off, 64);
        if (lane < 40) out[n * 40 + lane] = val - mx - logf(sum);
    }
}

extern "C" void kernel_launch(void* const* d_in, const int* in_sizes, int n_in,
                              void* d_out, int out_size, void* d_ws, size_t ws_size,
                              hipStream_t stream) {
    const float* x      = (const float*)d_in[0];
    const int*   ei     = (const int*)d_in[1];
    const float* W0     = (const float*)d_in[2];
    const float* a_src0 = (const float*)d_in[3];
    const float* a_dst0 = (const float*)d_in[4];
    const float* b0     = (const float*)d_in[5];
    const float* W1     = (const float*)d_in[6];
    const float* a_src1 = (const float*)d_in[7];
    const float* a_dst1 = (const float*)d_in[8];
    const float* b1     = (const float*)d_in[9];
    const float* W2     = (const float*)d_in[10];
    const float* a_src2 = (const float*)d_in[11];
    const float* a_dst2 = (const float*)d_in[12];
    const float* b2     = (const float*)d_in[13];

    const int N = in_sizes[0] / 128;          // 50000
    const int E_real = in_sizes[1] / 2;       // 800000
    const int E_tot = E_real + N;
    const int* src = ei;
    const int* dst = ei + E_real;

    unsigned char* ws = (unsigned char*)d_ws;
    const size_t szH = (size_t)N * 128 * sizeof(float);
    float* bufH     = (float*)(ws);
    float* bufAcc   = (float*)(ws + szH);
    float* als      = (float*)(ws + 2 * szH);
    float* ald      = (float*)(ws + 2 * szH + (size_t)N * 4 * sizeof(float));
    int*   offsets  = (int*)  (ws + 2 * szH + (size_t)N * 8 * sizeof(float));
    int*   counts   = offsets + (N + 1);
    int*   cursor   = counts + N;
    int*   blockTot = cursor + N;
    int*   blockPre = blockTot + 256;
    int*   csr_src  = blockPre + 256;         // E_tot ints

    const int B = 256;
    const int gRows64 = (N + 63) / 64;
    const int gEdge = (E_tot + B - 1) / B;
    const int SB    = (N + 1023) / 1024;
    const int gAgg  = 2048;

    // ===== CSR build (once) =====
    hipMemsetAsync(counts, 0, (size_t)N * sizeof(int), stream);
    hist_dst<<<gEdge, B, 0, stream>>>(dst, E_real, E_tot, counts);
    scanA<<<SB, B, 0, stream>>>(counts, offsets, blockTot, N);
    scanB<<<1, B, 0, stream>>>(blockTot, blockPre, offsets, SB, N);
    scanC<<<SB, B, 0, stream>>>(offsets, cursor, blockPre, N);
    scatter_src<<<gEdge, B, 0, stream>>>(src, dst, E_real, E_tot, cursor, csr_src);

    // ===== Layer 0 =====
    gemm_logits<128, 8, 4><<<gRows64, B, 0, stream>>>(x, W0, a_src0, a_dst0, bufH, als, ald, N);
    gat_agg128<<<gAgg, B, 0, stream>>>(offsets, csr_src, bufH, als, ald, b0, bufAcc, N);

    // ===== Layer 1 =====
    gemm_logits<128, 8, 4><<<gRows64, B, 0, stream>>>(bufAcc, W1, a_src1, a_dst1, bufH, als, ald, N);
    gat_agg128<<<gAgg, B, 0, stream>>>(offsets, csr_src, bufH, als, ald, b1, bufAcc, N);

    // ===== Layer 2 =====
    gemm_logits<40, 3, 1><<<gRows64, B, 0, stream>>>(bufAcc, W2, a_src2, a_dst2, bufH, als, ald, N);
    gat_agg40_lsm<<<gAgg, B, 0, stream>>>(offsets, csr_src, bufH, als, ald, b2,
                                          (float*)d_out, N);
}